// Round 4
// baseline (573.440 us; speedup 1.0000x reference)
//
#include <hip/hip_runtime.h>
#include <hip/hip_bf16.h>
#include <stdint.h>

typedef __bf16 bf16x8 __attribute__((ext_vector_type(8)));
typedef float f32x4 __attribute__((ext_vector_type(4)));
typedef float f32x16 __attribute__((ext_vector_type(16)));
typedef uint32_t u32x4 __attribute__((ext_vector_type(4)));
typedef unsigned short u16;

typedef __attribute__((address_space(1))) void as1_void;
typedef __attribute__((address_space(3))) void as3_void;

#define BAR() __builtin_amdgcn_s_barrier()
#define VMCNT(n) asm volatile("s_waitcnt vmcnt(" #n ")" ::: "memory")
#define LGKM0() asm volatile("s_waitcnt lgkmcnt(0)" ::: "memory")

__device__ __forceinline__ u16 f2bf(float f) {
  uint32_t u = __float_as_uint(f);
  u += 0x7fffu + ((u >> 16) & 1u);
  return (u16)(u >> 16);
}

__device__ __forceinline__ uint32_t cvtpk(float lo, float hi) {
  uint32_t r;
  asm("v_cvt_pk_bf16_f32 %0, %1, %2" : "=v"(r) : "v"(lo), "v"(hi));
  return r;
}

// ---------------- fp32 -> bf16 convert (all 8 weights, one dispatch) ----------------
__global__ __launch_bounds__(256) void cvt8_kernel(
    const float4* s0, const float4* s1, const float4* s2, const float4* s3,
    const float4* s4, const float4* s5, const float4* s6, const float4* s7,
    ushort4* d0, ushort4* d1, ushort4* d2, ushort4* d3,
    ushort4* d4, ushort4* d5, ushort4* d6, ushort4* d7) {
  const float4* s; ushort4* d;
  switch (blockIdx.y) {
    case 0: s = s0; d = d0; break;
    case 1: s = s1; d = d1; break;
    case 2: s = s2; d = d2; break;
    case 3: s = s3; d = d3; break;
    case 4: s = s4; d = d4; break;
    case 5: s = s5; d = d5; break;
    case 6: s = s6; d = d6; break;
    default: s = s7; d = d7; break;
  }
  int i = blockIdx.x * 256 + threadIdx.x;
  float4 v = s[i];
  ushort4 o;
  o.x = f2bf(v.x); o.y = f2bf(v.y); o.z = f2bf(v.z); o.w = f2bf(v.w);
  d[i] = o;
}

// ---------------- layernorm fp32 -> bf16, D=1024 ----------------
__global__ __launch_bounds__(256) void ln_kernel(const float* __restrict__ x,
                                                 const float* __restrict__ g,
                                                 const float* __restrict__ b,
                                                 u16* __restrict__ out) {
  int row = blockIdx.x;
  int t = threadIdx.x;
  const float4* xr = (const float4*)(x + (size_t)row * 1024);
  float4 v = xr[t];
  float s = v.x + v.y + v.z + v.w;
  float s2 = v.x * v.x + v.y * v.y + v.z * v.z + v.w * v.w;
#pragma unroll
  for (int off = 1; off < 64; off <<= 1) {
    s += __shfl_xor(s, off);
    s2 += __shfl_xor(s2, off);
  }
  __shared__ float red[8];
  int wv = t >> 6;
  if ((t & 63) == 0) { red[wv] = s; red[4 + wv] = s2; }
  __syncthreads();
  s = red[0] + red[1] + red[2] + red[3];
  s2 = red[4] + red[5] + red[6] + red[7];
  float mu = s * (1.0f / 1024.0f);
  float var = s2 * (1.0f / 1024.0f) - mu * mu;
  float rstd = rsqrtf(var + 1e-5f);
  const float4 gv = ((const float4*)g)[t];
  const float4 bv = ((const float4*)b)[t];
  ushort4 o;
  o.x = f2bf((v.x - mu) * rstd * gv.x + bv.x);
  o.y = f2bf((v.y - mu) * rstd * gv.y + bv.y);
  o.z = f2bf((v.z - mu) * rstd * gv.z + bv.z);
  o.w = f2bf((v.w - mu) * rstd * gv.w + bv.w);
  ((ushort4*)out)[(size_t)row * 256 + t] = o;
}

// ================= 128x128 GEMM (m97 structure) — small-M GEMMs =================
template <int MODE>
__global__ __launch_bounds__(256) void gemm_kernel(
    const u16* __restrict__ A, const u16* __restrict__ W,
    const float* __restrict__ bias,
    u16* __restrict__ outb, float* __restrict__ outf,
    const float* __restrict__ res, const float* __restrict__ gamma,
    int sk_shift, float ascale) {
  const int K = 1024, N = 1024;
  int m0 = blockIdx.x * 128, n0 = blockIdx.y * 128;
  int t = threadIdx.x, lane = t & 63, wv = t >> 6;
  int wr = wv >> 1, wc = wv & 1;
  int lr = lane & 15, lk = (lane >> 4) * 8;
  __shared__ u16 As[128 * 32];
  __shared__ u16 Ws[128 * 32];
  f32x4 acc[4][4] = {};
  for (int kt = 0; kt < K / 32; ++kt) {
#pragma unroll
    for (int i = 0; i < 2; ++i) {
      int c = i * 256 + t;
      int row = c >> 2, k8 = (c & 3) << 3;
      const u16* ga = A + (size_t)(m0 + row) * K + kt * 32 + k8;
      const u16* gw = W + (size_t)(n0 + row) * K + kt * 32 + k8;
      __builtin_amdgcn_global_load_lds((const as1_void*)ga, (as3_void*)(As + c * 8), 16, 0, 0);
      __builtin_amdgcn_global_load_lds((const as1_void*)gw, (as3_void*)(Ws + c * 8), 16, 0, 0);
    }
    __syncthreads();
    bf16x8 af[4], wf[4];
#pragma unroll
    for (int m = 0; m < 4; ++m)
      af[m] = *(const bf16x8*)(As + (wr * 64 + m * 16 + lr) * 32 + lk);
#pragma unroll
    for (int n = 0; n < 4; ++n)
      wf[n] = *(const bf16x8*)(Ws + (wc * 64 + n * 16 + lr) * 32 + lk);
#pragma unroll
    for (int m = 0; m < 4; ++m)
#pragma unroll
      for (int n = 0; n < 4; ++n)
        acc[m][n] = __builtin_amdgcn_mfma_f32_16x16x32_bf16(af[m], wf[n], acc[m][n], 0, 0, 0);
    __syncthreads();
  }
  int rowb = m0 + wr * 64 + (lane >> 4) * 4;
#pragma unroll
  for (int m = 0; m < 4; ++m) {
#pragma unroll
    for (int n = 0; n < 4; ++n) {
      int col = n0 + wc * 64 + n * 16 + lr;
      float bcol = bias[col];
#pragma unroll
      for (int r = 0; r < 4; ++r) {
        int row = rowb + m * 16 + r;
        float val = (acc[m][n][r] + bcol) * ascale;
        if (MODE == 0) {
          outb[(size_t)row * N + col] = f2bf(val);
        } else if (MODE == 1) {
          size_t idx = (size_t)row * N + col;
          outf[idx] = res[idx] + gamma[col] * val;
        } else {
          int bb = row >> sk_shift;
          int ss = row & ((1 << sk_shift) - 1);
          int h = col >> 6, d = col & 63;
          outb[((((size_t)bb * 16 + h) * 64 + d) << sk_shift) + ss] = f2bf(val);
        }
      }
    }
  }
}

// ================= 256x256 8-phase GEMM (T2+T3+T4+T5) — big-M GEMMs =================
template <int MODE>
__global__ __launch_bounds__(512, 2) void gemm256_kernel(
    const u16* __restrict__ A, const u16* __restrict__ W,
    const float* __restrict__ bias,
    u16* __restrict__ outb, float* __restrict__ outf,
    const float* __restrict__ res, const float* __restrict__ gamma,
    int mtiles, int sk_shift, float ascale) {
  const int K = 1024, N = 1024;
  int nwg = mtiles * 4;
  int cpx = nwg >> 3;
  int bid = blockIdx.x;
  int swz = (bid & 7) * cpx + (bid >> 3);
  int mt = swz >> 2, nt = swz & 3;
  int m0 = mt * 256, n0 = nt * 256;

  int t = threadIdx.x, lane = t & 63, wv = t >> 6;
  int wm = wv >> 2, wn = wv & 3;
  int lr = lane & 15, lg = lane >> 4;
  int sa0 = ((lg) ^ (lr & 7)) * 8;
  int sa1 = ((4 + lg) ^ (lr & 7)) * 8;

  __shared__ u16 AB[2][2][256 * 64];
  u16* ldsA0 = &AB[0][0][0];
  u16* ldsB0 = &AB[0][1][0];
  u16* ldsA1 = &AB[1][0][0];
  u16* ldsB1 = &AB[1][1][0];

  int r0 = t >> 3, c0 = t & 7;
  int cs0 = c0 ^ (r0 & 7);
  const u16* gA0 = A + (size_t)(m0 + r0) * K + cs0 * 8;
  const u16* gA1 = gA0 + (size_t)64 * K;
  const u16* gB0 = W + (size_t)(n0 + r0) * K + cs0 * 8;
  const u16* gB1 = gB0 + (size_t)64 * K;

  auto STG = [&](u16* ldsbase, const u16* g0, const u16* g1, int half, int kt) {
    __builtin_amdgcn_global_load_lds(
        (const as1_void*)(g0 + (size_t)half * 128 * K + kt * 64),
        (as3_void*)(ldsbase + (half * 128 + r0) * 64 + c0 * 8), 16, 0, 0);
    __builtin_amdgcn_global_load_lds(
        (const as1_void*)(g1 + (size_t)half * 128 * K + kt * 64),
        (as3_void*)(ldsbase + (half * 128 + r0 + 64) * 64 + c0 * 8), 16, 0, 0);
  };

  f32x4 acc[8][4] = {};
  bf16x8 aX[4][2], bX[2][2], bY[2][2];

  auto LD_A = [&](const u16* base, int mo) {
#pragma unroll
    for (int m = 0; m < 4; ++m) {
      const u16* rp = base + (wm * 128 + (mo + m) * 16 + lr) * 64;
      aX[m][0] = *(const bf16x8*)(rp + sa0);
      aX[m][1] = *(const bf16x8*)(rp + sa1);
    }
  };
  auto LD_B = [&](bf16x8 (&dst)[2][2], const u16* base, int no) {
#pragma unroll
    for (int n = 0; n < 2; ++n) {
      const u16* rp = base + (wn * 64 + (no + n) * 16 + lr) * 64;
      dst[n][0] = *(const bf16x8*)(rp + sa0);
      dst[n][1] = *(const bf16x8*)(rp + sa1);
    }
  };
  auto QD = [&](bf16x8 (&bf)[2][2], int mo, int no) {
#pragma unroll
    for (int m = 0; m < 4; ++m)
#pragma unroll
      for (int n = 0; n < 2; ++n) {
        acc[mo + m][no + n] = __builtin_amdgcn_mfma_f32_16x16x32_bf16(
            aX[m][0], bf[n][0], acc[mo + m][no + n], 0, 0, 0);
        acc[mo + m][no + n] = __builtin_amdgcn_mfma_f32_16x16x32_bf16(
            aX[m][1], bf[n][1], acc[mo + m][no + n], 0, 0, 0);
      }
  };

  STG(ldsA0, gA0, gA1, 0, 0); STG(ldsA0, gA0, gA1, 1, 0);
  STG(ldsB0, gB0, gB1, 0, 0); STG(ldsB0, gB0, gB1, 1, 0);
  STG(ldsA1, gA0, gA1, 0, 1); STG(ldsA1, gA0, gA1, 1, 1);
  STG(ldsB1, gB0, gB1, 0, 1); STG(ldsB1, gB0, gB1, 1, 1);
  VMCNT(8);
  BAR();

  const int NIT = K / 128;
#pragma unroll 1
  for (int it = 0; it < NIT; ++it) {
    bool st = (it + 1 < NIT);
    int ktA = 2 * it;
    LD_A(ldsA0, 0); LD_B(bX, ldsB0, 0);
    BAR(); LGKM0();
    __builtin_amdgcn_s_setprio(1); QD(bX, 0, 0); __builtin_amdgcn_s_setprio(0);
    BAR();
    LD_B(bY, ldsB0, 2);
    BAR(); LGKM0();
    __builtin_amdgcn_s_setprio(1); QD(bY, 0, 2); __builtin_amdgcn_s_setprio(0);
    BAR();
    LD_A(ldsA0, 4);
    if (st) { STG(ldsB0, gB0, gB1, 0, ktA + 2); STG(ldsB0, gB0, gB1, 1, ktA + 2); }
    BAR(); LGKM0();
    __builtin_amdgcn_s_setprio(1); QD(bY, 4, 2); __builtin_amdgcn_s_setprio(0);
    BAR();
    if (st) { STG(ldsA0, gA0, gA1, 0, ktA + 2); STG(ldsA0, gA0, gA1, 1, ktA + 2); }
    if (st) { VMCNT(8); } else { VMCNT(0); }
    BAR();
    __builtin_amdgcn_s_setprio(1); QD(bX, 4, 0); __builtin_amdgcn_s_setprio(0);
    BAR();
    LD_A(ldsA1, 0); LD_B(bX, ldsB1, 0);
    BAR(); LGKM0();
    __builtin_amdgcn_s_setprio(1); QD(bX, 0, 0); __builtin_amdgcn_s_setprio(0);
    BAR();
    LD_B(bY, ldsB1, 2);
    BAR(); LGKM0();
    __builtin_amdgcn_s_setprio(1); QD(bY, 0, 2); __builtin_amdgcn_s_setprio(0);
    BAR();
    LD_A(ldsA1, 4);
    if (st) { STG(ldsB1, gB0, gB1, 0, ktA + 3); STG(ldsB1, gB0, gB1, 1, ktA + 3); }
    BAR(); LGKM0();
    __builtin_amdgcn_s_setprio(1); QD(bY, 4, 2); __builtin_amdgcn_s_setprio(0);
    BAR();
    if (st) { STG(ldsA1, gA0, gA1, 0, ktA + 3); STG(ldsA1, gA0, gA1, 1, ktA + 3); }
    if (st) { VMCNT(8); }
    BAR();
    __builtin_amdgcn_s_setprio(1); QD(bX, 4, 0); __builtin_amdgcn_s_setprio(0);
    BAR();
  }

  int rowb = m0 + wm * 128 + lg * 4;
#pragma unroll
  for (int mi = 0; mi < 8; ++mi) {
#pragma unroll
    for (int n = 0; n < 4; ++n) {
      int col = n0 + wn * 64 + n * 16 + lr;
      float bcol = bias[col];
#pragma unroll
      for (int r = 0; r < 4; ++r) {
        int row = rowb + mi * 16 + r;
        float val = (acc[mi][n][r] + bcol) * ascale;
        if (MODE == 0) {
          outb[(size_t)row * N + col] = f2bf(val);
        } else if (MODE == 1) {
          size_t idx = (size_t)row * N + col;
          outf[idx] = res[idx] + gamma[col] * val;
        } else {
          int bb = row >> sk_shift;
          int ss = row & ((1 << sk_shift) - 1);
          int h = col >> 6, d = col & 63;
          outb[((((size_t)bb * 16 + h) * 64 + d) << sk_shift) + ss] = f2bf(val);
        }
      }
    }
  }
}

// ---------------- flash attention v2: swapped QK^T, 32x32x16, in-register softmax ----------------
// Q: [B*Sq, 1024] bf16 (pre-scaled by 0.125*log2e); K: [B*Sk, 1024] bf16; Vt: [B*16, 64, Sk] bf16.
// ctx out: [B*Sq, 1024] bf16. Block = 256 thr (4 waves x 32 q-rows = 128 q-rows).
// No LDS. K rows are MFMA A-frags, Vt rows are MFMA B-frags, read direct from global (L2-resident,
// XCD-grouped grid). P stays in registers: cvt_pk_bf16 + permlane32_swap builds PV A-frags.
__global__ __launch_bounds__(256, 4) void attn_kernel(
    const u16* __restrict__ Q, const u16* __restrict__ Kmat,
    const u16* __restrict__ Vt, u16* __restrict__ ctx,
    int Sq, int Sk, int nq_shift) {
  int f = blockIdx.x;
  int xcd = f & 7, slot = f >> 3;
  int group = xcd * 16 + (slot >> nq_shift);
  int qt = slot & ((1 << nq_shift) - 1);
  int b = group >> 4, h = group & 15;
  int t = threadIdx.x, lane = t & 63, wv = t >> 6;
  int l31 = lane & 31, hi = lane >> 5;

  int q0 = qt * 128 + wv * 32;
  // Q as B-operand: lane holds Q[q=l31][d = ds*16 + hi*8 + j]
  const u16* Qb = Q + (size_t)(b * Sq + q0 + l31) * 1024 + h * 64 + hi * 8;
  bf16x8 qf[4];
#pragma unroll
  for (int ds = 0; ds < 4; ++ds) qf[ds] = *(const bf16x8*)(Qb + ds * 16);

  const u16* Kb = Kmat + (size_t)(b * Sk + l31) * 1024 + h * 64 + hi * 8;
  const u16* Vb0 = Vt + (size_t)((b * 16 + h) * 64 + l31) * Sk + hi * 8;
  const u16* Vb1 = Vb0 + (size_t)32 * Sk;

  f32x16 acc0 = {}, acc1 = {};
  float m_run = -1e30f, l_run = 0.f;

  int nt = Sk >> 5;  // KVBLK = 32
  for (int kt = 0; kt < nt; ++kt) {
    // ---- QK^T (swapped): S^T[k, q] ----
    const u16* kp = Kb + (size_t)(kt * 32) * 1024;
    f32x16 s = {};
#pragma unroll
    for (int ds = 0; ds < 4; ++ds) {
      bf16x8 ka = *(const bf16x8*)(kp + ds * 16);
      s = __builtin_amdgcn_mfma_f32_32x32x16_bf16(ka, qf[ds], s, 0, 0, 0);
    }
    // V frags (independent of softmax; issue early)
    bf16x8 vf0[2], vf1[2];
#pragma unroll
    for (int ks = 0; ks < 2; ++ks) {
      vf0[ks] = *(const bf16x8*)(Vb0 + kt * 32 + ks * 16);
      vf1[ks] = *(const bf16x8*)(Vb1 + kt * 32 + ks * 16);
    }
    // ---- online softmax, in-register (lane owns q = l31) ----
    float mx = s[0];
#pragma unroll
    for (int i = 1; i < 16; ++i) mx = fmaxf(mx, s[i]);
    mx = fmaxf(mx, __shfl_xor(mx, 32));
    if (__any(mx > m_run + 8.f)) {  // defer-max: rescale rarely (always at kt==0)
      float mnew = fmaxf(m_run, mx);
      float fac = __builtin_amdgcn_exp2f(m_run - mnew);
#pragma unroll
      for (int r = 0; r < 16; ++r) {
        int src = (r & 3) + 8 * (r >> 2) + 4 * hi;
        float fr = __shfl(fac, src);
        acc0[r] *= fr;
        acc1[r] *= fr;
      }
      l_run *= fac;
      m_run = mnew;
    }
    float sum = 0.f;
#pragma unroll
    for (int i = 0; i < 16; ++i) {
      s[i] = __builtin_amdgcn_exp2f(s[i] - m_run);
      sum += s[i];
    }
    sum += __shfl_xor(sum, 32);
    l_run += sum;
    // ---- pack P into PV A-frags: cvt_pk + permlane32_swap ----
    bf16x8 pa[2];
#pragma unroll
    for (int half = 0; half < 2; ++half) {
      int o = half * 8;
      uint32_t a0 = cvtpk(s[o + 0], s[o + 1]);
      uint32_t a1 = cvtpk(s[o + 2], s[o + 3]);
      uint32_t b0 = cvtpk(s[o + 4], s[o + 5]);
      uint32_t b1 = cvtpk(s[o + 6], s[o + 7]);
      asm("v_permlane32_swap_b32 %0, %1" : "+v"(a0), "+v"(b0));
      asm("v_permlane32_swap_b32 %0, %1" : "+v"(a1), "+v"(b1));
      u32x4 w;
      w[0] = a0; w[1] = a1; w[2] = b0; w[3] = b1;
      pa[half] = __builtin_bit_cast(bf16x8, w);
    }
    // ---- PV: O[q, d] ----
#pragma unroll
    for (int ks = 0; ks < 2; ++ks) {
      acc0 = __builtin_amdgcn_mfma_f32_32x32x16_bf16(pa[ks], vf0[ks], acc0, 0, 0, 0);
      acc1 = __builtin_amdgcn_mfma_f32_32x32x16_bf16(pa[ks], vf1[ks], acc1, 0, 0, 0);
    }
  }
  // ---- epilogue: normalize (l lives in lane-q space; acc rows are q=crow(r,hi)) ----
  float linv = 1.0f / l_run;
  u16* cb = ctx + (size_t)(b * Sq + q0) * 1024 + h * 64;
#pragma unroll
  for (int r = 0; r < 16; ++r) {
    int src = (r & 3) + 8 * (r >> 2) + 4 * hi;
    float li = __shfl(linv, src);
    cb[(size_t)src * 1024 + l31] = f2bf(acc0[r] * li);
    cb[(size_t)src * 1024 + 32 + l31] = f2bf(acc1[r] * li);
  }
}

extern "C" void kernel_launch(void* const* d_in, const int* in_sizes, int n_in,
                              void* d_out, int out_size, void* d_ws, size_t ws_size,
                              hipStream_t stream) {
  const float* v = (const float*)d_in[0];
  const float* l = (const float*)d_in[1];
  const float* ln_v_g = (const float*)d_in[2];
  const float* ln_v_b = (const float*)d_in[3];
  const float* ln_l_g = (const float*)d_in[4];
  const float* ln_l_b = (const float*)d_in[5];
  const float* gamma_v = (const float*)d_in[6];
  const float* gamma_l = (const float*)d_in[7];
  const float* Wf[8];
  const float* Bf[8];
  for (int i = 0; i < 8; ++i) {
    Wf[i] = (const float*)d_in[8 + 2 * i];
    Bf[i] = (const float*)d_in[9 + 2 * i];
  }
  float* v_out = (float*)d_out;
  float* l_out = v_out + (size_t)16384 * 1024;

  char* p = (char*)d_ws;
  auto alloc = [&](size_t bytes) {
    char* r = p;
    p += (bytes + 255) & ~(size_t)255;
    return r;
  };
  u16* Wbf[8];
  for (int i = 0; i < 8; ++i) Wbf[i] = (u16*)alloc((size_t)1024 * 1024 * 2);
  u16* vn   = (u16*)alloc((size_t)16384 * 1024 * 2);
  u16* lnm  = (u16*)alloc((size_t)4096 * 1024 * 2);
  u16* bufA = (u16*)alloc((size_t)16384 * 1024 * 2);
  u16* bufB = (u16*)alloc((size_t)4096 * 1024 * 2);
  u16* bufC = (u16*)alloc((size_t)4096 * 1024 * 2);
  u16* bufD = (u16*)alloc((size_t)16384 * 1024 * 2);

  const float QSC = 0.125f * 1.4426950408889634f;  // fold 1/sqrt(64) and log2(e) into Q

  cvt8_kernel<<<dim3(1024, 8), 256, 0, stream>>>(
      (const float4*)Wf[0], (const float4*)Wf[1], (const float4*)Wf[2], (const float4*)Wf[3],
      (const float4*)Wf[4], (const float4*)Wf[5], (const float4*)Wf[6], (const float4*)Wf[7],
      (ushort4*)Wbf[0], (ushort4*)Wbf[1], (ushort4*)Wbf[2], (ushort4*)Wbf[3],
      (ushort4*)Wbf[4], (ushort4*)Wbf[5], (ushort4*)Wbf[6], (ushort4*)Wbf[7]);
  ln_kernel<<<16384, 256, 0, stream>>>(v, ln_v_g, ln_v_b, vn);
  ln_kernel<<<4096, 256, 0, stream>>>(l, ln_l_g, ln_l_b, lnm);

  dim3 blk(256);
  dim3 blk512(512);
  // ---- v2l: q = v_norm, k/v = l_norm ----
  gemm256_kernel<0><<<dim3(256), blk512, 0, stream>>>(vn, Wbf[0], Bf[0], bufA, nullptr, nullptr, nullptr, 64, 0, QSC);
  gemm_kernel<0><<<dim3(32, 8), blk, 0, stream>>>(lnm, Wbf[1], Bf[1], bufB, nullptr, nullptr, nullptr, 0, 1.0f);
  gemm_kernel<2><<<dim3(32, 8), blk, 0, stream>>>(lnm, Wbf[2], Bf[2], bufC, nullptr, nullptr, nullptr, 9, 1.0f);
  attn_kernel<<<dim3(2048), blk, 0, stream>>>(bufA, bufB, bufC, bufD, 2048, 512, 4);
  gemm256_kernel<1><<<dim3(256), blk512, 0, stream>>>(bufD, Wbf[3], Bf[3], nullptr, v_out, v, gamma_v, 64, 0, 1.0f);
  // ---- l2v: q = l_norm, k/v = v_norm ----
  gemm_kernel<0><<<dim3(32, 8), blk, 0, stream>>>(lnm, Wbf[4], Bf[4], bufB, nullptr, nullptr, nullptr, 0, QSC);
  gemm256_kernel<0><<<dim3(256), blk512, 0, stream>>>(vn, Wbf[5], Bf[5], bufA, nullptr, nullptr, nullptr, 64, 0, 1.0f);
  gemm256_kernel<2><<<dim3(256), blk512, 0, stream>>>(vn, Wbf[6], Bf[6], bufD, nullptr, nullptr, nullptr, 64, 11, 1.0f);
  attn_kernel<<<dim3(512), blk, 0, stream>>>(bufB, bufA, bufD, bufC, 512, 2048, 2);
  gemm_kernel<1><<<dim3(32, 8), blk, 0, stream>>>(bufC, Wbf[7], Bf[7], nullptr, l_out, l, gamma_l, 0, 1.0f);
}

// Round 5
// 434.979 us; speedup vs baseline: 1.3183x; 1.3183x over previous
//
#include <hip/hip_runtime.h>
#include <hip/hip_bf16.h>
#include <stdint.h>

typedef __bf16 bf16x8 __attribute__((ext_vector_type(8)));
typedef float f32x4 __attribute__((ext_vector_type(4)));
typedef float f32x16 __attribute__((ext_vector_type(16)));
typedef uint32_t u32x4 __attribute__((ext_vector_type(4)));
typedef unsigned short u16;

typedef __attribute__((address_space(1))) void as1_void;
typedef __attribute__((address_space(3))) void as3_void;

#define BAR() __builtin_amdgcn_s_barrier()
#define VMCNT(n) asm volatile("s_waitcnt vmcnt(" #n ")" ::: "memory")
#define LGKM0() asm volatile("s_waitcnt lgkmcnt(0)" ::: "memory")

__device__ __forceinline__ u16 f2bf(float f) {
  uint32_t u = __float_as_uint(f);
  u += 0x7fffu + ((u >> 16) & 1u);
  return (u16)(u >> 16);
}

__device__ __forceinline__ uint32_t cvtpk(float lo, float hi) {
  uint32_t r;
  asm("v_cvt_pk_bf16_f32 %0, %1, %2" : "=v"(r) : "v"(lo), "v"(hi));
  return r;
}

// ---------------- fp32 -> bf16 convert (all 8 weights, one dispatch) ----------------
__global__ __launch_bounds__(256) void cvt8_kernel(
    const float4* s0, const float4* s1, const float4* s2, const float4* s3,
    const float4* s4, const float4* s5, const float4* s6, const float4* s7,
    ushort4* d0, ushort4* d1, ushort4* d2, ushort4* d3,
    ushort4* d4, ushort4* d5, ushort4* d6, ushort4* d7) {
  const float4* s; ushort4* d;
  switch (blockIdx.y) {
    case 0: s = s0; d = d0; break;
    case 1: s = s1; d = d1; break;
    case 2: s = s2; d = d2; break;
    case 3: s = s3; d = d3; break;
    case 4: s = s4; d = d4; break;
    case 5: s = s5; d = d5; break;
    case 6: s = s6; d = d6; break;
    default: s = s7; d = d7; break;
  }
  int i = blockIdx.x * 256 + threadIdx.x;
  float4 v = s[i];
  ushort4 o;
  o.x = f2bf(v.x); o.y = f2bf(v.y); o.z = f2bf(v.z); o.w = f2bf(v.w);
  d[i] = o;
}

// ---------------- layernorm fp32 -> bf16, D=1024 ----------------
__global__ __launch_bounds__(256) void ln_kernel(const float* __restrict__ x,
                                                 const float* __restrict__ g,
                                                 const float* __restrict__ b,
                                                 u16* __restrict__ out) {
  int row = blockIdx.x;
  int t = threadIdx.x;
  const float4* xr = (const float4*)(x + (size_t)row * 1024);
  float4 v = xr[t];
  float s = v.x + v.y + v.z + v.w;
  float s2 = v.x * v.x + v.y * v.y + v.z * v.z + v.w * v.w;
#pragma unroll
  for (int off = 1; off < 64; off <<= 1) {
    s += __shfl_xor(s, off);
    s2 += __shfl_xor(s2, off);
  }
  __shared__ float red[8];
  int wv = t >> 6;
  if ((t & 63) == 0) { red[wv] = s; red[4 + wv] = s2; }
  __syncthreads();
  s = red[0] + red[1] + red[2] + red[3];
  s2 = red[4] + red[5] + red[6] + red[7];
  float mu = s * (1.0f / 1024.0f);
  float var = s2 * (1.0f / 1024.0f) - mu * mu;
  float rstd = rsqrtf(var + 1e-5f);
  const float4 gv = ((const float4*)g)[t];
  const float4 bv = ((const float4*)b)[t];
  ushort4 o;
  o.x = f2bf((v.x - mu) * rstd * gv.x + bv.x);
  o.y = f2bf((v.y - mu) * rstd * gv.y + bv.y);
  o.z = f2bf((v.z - mu) * rstd * gv.z + bv.z);
  o.w = f2bf((v.w - mu) * rstd * gv.w + bv.w);
  ((ushort4*)out)[(size_t)row * 256 + t] = o;
}

// ================= 128x128 GEMM (m97 structure) — small-M GEMMs =================
template <int MODE>
__global__ __launch_bounds__(256) void gemm_kernel(
    const u16* __restrict__ A, const u16* __restrict__ W,
    const float* __restrict__ bias,
    u16* __restrict__ outb, float* __restrict__ outf,
    const float* __restrict__ res, const float* __restrict__ gamma,
    int sk_shift, float ascale) {
  const int K = 1024, N = 1024;
  int m0 = blockIdx.x * 128, n0 = blockIdx.y * 128;
  int t = threadIdx.x, lane = t & 63, wv = t >> 6;
  int wr = wv >> 1, wc = wv & 1;
  int lr = lane & 15, lk = (lane >> 4) * 8;
  __shared__ u16 As[128 * 32];
  __shared__ u16 Ws[128 * 32];
  f32x4 acc[4][4] = {};
  for (int kt = 0; kt < K / 32; ++kt) {
#pragma unroll
    for (int i = 0; i < 2; ++i) {
      int c = i * 256 + t;
      int row = c >> 2, k8 = (c & 3) << 3;
      const u16* ga = A + (size_t)(m0 + row) * K + kt * 32 + k8;
      const u16* gw = W + (size_t)(n0 + row) * K + kt * 32 + k8;
      __builtin_amdgcn_global_load_lds((const as1_void*)ga, (as3_void*)(As + c * 8), 16, 0, 0);
      __builtin_amdgcn_global_load_lds((const as1_void*)gw, (as3_void*)(Ws + c * 8), 16, 0, 0);
    }
    __syncthreads();
    bf16x8 af[4], wf[4];
#pragma unroll
    for (int m = 0; m < 4; ++m)
      af[m] = *(const bf16x8*)(As + (wr * 64 + m * 16 + lr) * 32 + lk);
#pragma unroll
    for (int n = 0; n < 4; ++n)
      wf[n] = *(const bf16x8*)(Ws + (wc * 64 + n * 16 + lr) * 32 + lk);
#pragma unroll
    for (int m = 0; m < 4; ++m)
#pragma unroll
      for (int n = 0; n < 4; ++n)
        acc[m][n] = __builtin_amdgcn_mfma_f32_16x16x32_bf16(af[m], wf[n], acc[m][n], 0, 0, 0);
    __syncthreads();
  }
  int rowb = m0 + wr * 64 + (lane >> 4) * 4;
#pragma unroll
  for (int m = 0; m < 4; ++m) {
#pragma unroll
    for (int n = 0; n < 4; ++n) {
      int col = n0 + wc * 64 + n * 16 + lr;
      float bcol = bias[col];
#pragma unroll
      for (int r = 0; r < 4; ++r) {
        int row = rowb + m * 16 + r;
        float val = (acc[m][n][r] + bcol) * ascale;
        if (MODE == 0) {
          outb[(size_t)row * N + col] = f2bf(val);
        } else if (MODE == 1) {
          size_t idx = (size_t)row * N + col;
          outf[idx] = res[idx] + gamma[col] * val;
        } else {
          int bb = row >> sk_shift;
          int ss = row & ((1 << sk_shift) - 1);
          int h = col >> 6, d = col & 63;
          outb[((((size_t)bb * 16 + h) * 64 + d) << sk_shift) + ss] = f2bf(val);
        }
      }
    }
  }
}

// ================= 256x256 8-phase GEMM (T2+T3+T4+T5) — big-M GEMMs =================
template <int MODE>
__global__ __launch_bounds__(512, 2) void gemm256_kernel(
    const u16* __restrict__ A, const u16* __restrict__ W,
    const float* __restrict__ bias,
    u16* __restrict__ outb, float* __restrict__ outf,
    const float* __restrict__ res, const float* __restrict__ gamma,
    int mtiles, int sk_shift, float ascale) {
  const int K = 1024, N = 1024;
  int nwg = mtiles * 4;
  int cpx = nwg >> 3;
  int bid = blockIdx.x;
  int swz = (bid & 7) * cpx + (bid >> 3);
  int mt = swz >> 2, nt = swz & 3;
  int m0 = mt * 256, n0 = nt * 256;

  int t = threadIdx.x, lane = t & 63, wv = t >> 6;
  int wm = wv >> 2, wn = wv & 3;
  int lr = lane & 15, lg = lane >> 4;
  int sa0 = ((lg) ^ (lr & 7)) * 8;
  int sa1 = ((4 + lg) ^ (lr & 7)) * 8;

  __shared__ u16 AB[2][2][256 * 64];
  u16* ldsA0 = &AB[0][0][0];
  u16* ldsB0 = &AB[0][1][0];
  u16* ldsA1 = &AB[1][0][0];
  u16* ldsB1 = &AB[1][1][0];

  int r0 = t >> 3, c0 = t & 7;
  int cs0 = c0 ^ (r0 & 7);
  const u16* gA0 = A + (size_t)(m0 + r0) * K + cs0 * 8;
  const u16* gA1 = gA0 + (size_t)64 * K;
  const u16* gB0 = W + (size_t)(n0 + r0) * K + cs0 * 8;
  const u16* gB1 = gB0 + (size_t)64 * K;

  auto STG = [&](u16* ldsbase, const u16* g0, const u16* g1, int half, int kt) {
    __builtin_amdgcn_global_load_lds(
        (const as1_void*)(g0 + (size_t)half * 128 * K + kt * 64),
        (as3_void*)(ldsbase + (half * 128 + r0) * 64 + c0 * 8), 16, 0, 0);
    __builtin_amdgcn_global_load_lds(
        (const as1_void*)(g1 + (size_t)half * 128 * K + kt * 64),
        (as3_void*)(ldsbase + (half * 128 + r0 + 64) * 64 + c0 * 8), 16, 0, 0);
  };

  f32x4 acc[8][4] = {};
  bf16x8 aX[4][2], bX[2][2], bY[2][2];

  auto LD_A = [&](const u16* base, int mo) {
#pragma unroll
    for (int m = 0; m < 4; ++m) {
      const u16* rp = base + (wm * 128 + (mo + m) * 16 + lr) * 64;
      aX[m][0] = *(const bf16x8*)(rp + sa0);
      aX[m][1] = *(const bf16x8*)(rp + sa1);
    }
  };
  auto LD_B = [&](bf16x8 (&dst)[2][2], const u16* base, int no) {
#pragma unroll
    for (int n = 0; n < 2; ++n) {
      const u16* rp = base + (wn * 64 + (no + n) * 16 + lr) * 64;
      dst[n][0] = *(const bf16x8*)(rp + sa0);
      dst[n][1] = *(const bf16x8*)(rp + sa1);
    }
  };
  auto QD = [&](bf16x8 (&bf)[2][2], int mo, int no) {
#pragma unroll
    for (int m = 0; m < 4; ++m)
#pragma unroll
      for (int n = 0; n < 2; ++n) {
        acc[mo + m][no + n] = __builtin_amdgcn_mfma_f32_16x16x32_bf16(
            aX[m][0], bf[n][0], acc[mo + m][no + n], 0, 0, 0);
        acc[mo + m][no + n] = __builtin_amdgcn_mfma_f32_16x16x32_bf16(
            aX[m][1], bf[n][1], acc[mo + m][no + n], 0, 0, 0);
      }
  };

  STG(ldsA0, gA0, gA1, 0, 0); STG(ldsA0, gA0, gA1, 1, 0);
  STG(ldsB0, gB0, gB1, 0, 0); STG(ldsB0, gB0, gB1, 1, 0);
  STG(ldsA1, gA0, gA1, 0, 1); STG(ldsA1, gA0, gA1, 1, 1);
  STG(ldsB1, gB0, gB1, 0, 1); STG(ldsB1, gB0, gB1, 1, 1);
  VMCNT(8);
  BAR();

  const int NIT = K / 128;
#pragma unroll 1
  for (int it = 0; it < NIT; ++it) {
    bool st = (it + 1 < NIT);
    int ktA = 2 * it;
    LD_A(ldsA0, 0); LD_B(bX, ldsB0, 0);
    BAR(); LGKM0();
    __builtin_amdgcn_s_setprio(1); QD(bX, 0, 0); __builtin_amdgcn_s_setprio(0);
    BAR();
    LD_B(bY, ldsB0, 2);
    BAR(); LGKM0();
    __builtin_amdgcn_s_setprio(1); QD(bY, 0, 2); __builtin_amdgcn_s_setprio(0);
    BAR();
    LD_A(ldsA0, 4);
    if (st) { STG(ldsB0, gB0, gB1, 0, ktA + 2); STG(ldsB0, gB0, gB1, 1, ktA + 2); }
    BAR(); LGKM0();
    __builtin_amdgcn_s_setprio(1); QD(bY, 4, 2); __builtin_amdgcn_s_setprio(0);
    BAR();
    if (st) { STG(ldsA0, gA0, gA1, 0, ktA + 2); STG(ldsA0, gA0, gA1, 1, ktA + 2); }
    if (st) { VMCNT(8); } else { VMCNT(0); }
    BAR();
    __builtin_amdgcn_s_setprio(1); QD(bX, 4, 0); __builtin_amdgcn_s_setprio(0);
    BAR();
    LD_A(ldsA1, 0); LD_B(bX, ldsB1, 0);
    BAR(); LGKM0();
    __builtin_amdgcn_s_setprio(1); QD(bX, 0, 0); __builtin_amdgcn_s_setprio(0);
    BAR();
    LD_B(bY, ldsB1, 2);
    BAR(); LGKM0();
    __builtin_amdgcn_s_setprio(1); QD(bY, 0, 2); __builtin_amdgcn_s_setprio(0);
    BAR();
    LD_A(ldsA1, 4);
    if (st) { STG(ldsB1, gB0, gB1, 0, ktA + 3); STG(ldsB1, gB0, gB1, 1, ktA + 3); }
    BAR(); LGKM0();
    __builtin_amdgcn_s_setprio(1); QD(bY, 4, 2); __builtin_amdgcn_s_setprio(0);
    BAR();
    if (st) { STG(ldsA1, gA0, gA1, 0, ktA + 3); STG(ldsA1, gA0, gA1, 1, ktA + 3); }
    if (st) { VMCNT(8); }
    BAR();
    __builtin_amdgcn_s_setprio(1); QD(bX, 4, 0); __builtin_amdgcn_s_setprio(0);
    BAR();
  }

  int rowb = m0 + wm * 128 + lg * 4;
#pragma unroll
  for (int mi = 0; mi < 8; ++mi) {
#pragma unroll
    for (int n = 0; n < 4; ++n) {
      int col = n0 + wn * 64 + n * 16 + lr;
      float bcol = bias[col];
#pragma unroll
      for (int r = 0; r < 4; ++r) {
        int row = rowb + mi * 16 + r;
        float val = (acc[mi][n][r] + bcol) * ascale;
        if (MODE == 0) {
          outb[(size_t)row * N + col] = f2bf(val);
        } else if (MODE == 1) {
          size_t idx = (size_t)row * N + col;
          outf[idx] = res[idx] + gamma[col] * val;
        } else {
          int bb = row >> sk_shift;
          int ss = row & ((1 << sk_shift) - 1);
          int h = col >> 6, d = col & 63;
          outb[((((size_t)bb * 16 + h) * 64 + d) << sk_shift) + ss] = f2bf(val);
        }
      }
    }
  }
}

// ---------------- flash attention v3: swapped QK^T 32x32, in-reg softmax, LDS-staged K/V ----------------
// Q: [B*Sq, 1024] bf16 (Q-side pre-scaled by 0.125*log2e); K: [B*Sk, 1024] bf16;
// Vt: [B*16, 64, Sk] bf16; ctx out: [B*Sq, 1024] bf16.
// 256 thr = 4 waves x 32 q-rows = 128 q-rows/block. KVBLK=64: K-tile [64k][64d] and
// Vt-tile [64d][64k] staged via global_load_lds (XOR-swizzled via pre-swizzled global
// source), double-buffered, stage(t+1) issued before compute(t). No P LDS.
__global__ __launch_bounds__(256, 4) void attn_kernel(
    const u16* __restrict__ Q, const u16* __restrict__ Kmat,
    const u16* __restrict__ Vt, u16* __restrict__ ctx,
    int Sq, int Sk, int nq_shift) {
  int f = blockIdx.x;
  int xcd = f & 7, slot = f >> 3;
  int group = xcd * 16 + (slot >> nq_shift);
  int qt = slot & ((1 << nq_shift) - 1);
  int b = group >> 4, h = group & 15;
  int t = threadIdx.x, lane = t & 63, wv = t >> 6;
  int l31 = lane & 31, hi = lane >> 5;

  __shared__ u16 Ks[2][64 * 64];
  __shared__ u16 Vs[2][64 * 64];

  int q0 = qt * 128 + wv * 32;
  // Q as B-operand: lane holds Q[q=l31][d = ds*16 + hi*8 + j]
  const u16* Qb = Q + (size_t)(b * Sq + q0 + l31) * 1024 + h * 64 + hi * 8;
  bf16x8 qf[4];
#pragma unroll
  for (int ds = 0; ds < 4; ++ds) qf[ds] = *(const bf16x8*)(Qb + ds * 16);

  // staging: thread t owns LDS blocks t and 256+t of each tile (row = blk>>3, c = blk&7);
  // source is the swizzled block (c ^ (row&7)) — linear dest + inverse-swizzled source.
  int trow = t >> 3, tc = t & 7;
  int sc = (tc ^ (trow & 7)) * 8;
  const u16* gk = Kmat + (size_t)(b * Sk + trow) * 1024 + h * 64 + sc;
  const u16* gv = Vt + (size_t)((b * 16 + h) * 64 + trow) * Sk + sc;

  auto STAGE = [&](int buf, int kt) {
    const u16* k0 = gk + (size_t)(kt * 64) * 1024;
    const u16* v0 = gv + kt * 64;
    __builtin_amdgcn_global_load_lds((const as1_void*)k0, (as3_void*)(Ks[buf] + t * 8), 16, 0, 0);
    __builtin_amdgcn_global_load_lds((const as1_void*)(k0 + (size_t)32 * 1024), (as3_void*)(Ks[buf] + 2048 + t * 8), 16, 0, 0);
    __builtin_amdgcn_global_load_lds((const as1_void*)v0, (as3_void*)(Vs[buf] + t * 8), 16, 0, 0);
    __builtin_amdgcn_global_load_lds((const as1_void*)(v0 + (size_t)32 * Sk), (as3_void*)(Vs[buf] + 2048 + t * 8), 16, 0, 0);
  };

  STAGE(0, 0);
  __syncthreads();

  f32x16 acc0 = {}, acc1 = {};
  float m_run = -1e30f, l_run = 0.f;
  int sw = l31 & 7;

  int nt = Sk >> 6;
  for (int kt = 0; kt < nt; ++kt) {
    int cur = kt & 1;
    if (kt + 1 < nt) STAGE(cur ^ 1, kt + 1);
    // ---- QK^T (swapped): S^T[k, q], two 32-k sub-blocks ----
    const u16* kb = Ks[cur];
    f32x16 s0v = {}, s1v = {};
    __builtin_amdgcn_s_setprio(1);
#pragma unroll
    for (int ds = 0; ds < 4; ++ds) {
      int blk = 2 * ds + hi;
      bf16x8 ka0 = *(const bf16x8*)(kb + l31 * 64 + ((blk ^ sw) * 8));
      bf16x8 ka1 = *(const bf16x8*)(kb + (32 + l31) * 64 + ((blk ^ sw) * 8));
      s0v = __builtin_amdgcn_mfma_f32_32x32x16_bf16(ka0, qf[ds], s0v, 0, 0, 0);
      s1v = __builtin_amdgcn_mfma_f32_32x32x16_bf16(ka1, qf[ds], s1v, 0, 0, 0);
    }
    __builtin_amdgcn_s_setprio(0);
    // ---- online softmax, in-register (lane owns q = l31 per hi-half) ----
    float mx = s0v[0];
#pragma unroll
    for (int i = 1; i < 16; ++i) mx = fmaxf(mx, s0v[i]);
#pragma unroll
    for (int i = 0; i < 16; ++i) mx = fmaxf(mx, s1v[i]);
    mx = fmaxf(mx, __shfl_xor(mx, 32));
    if (__any(mx > m_run + 8.f)) {  // defer-max; always true at kt==0
      float mnew = fmaxf(m_run, mx);
      float fac = __builtin_amdgcn_exp2f(m_run - mnew);
#pragma unroll
      for (int r = 0; r < 16; ++r) {
        int src = (r & 3) + 8 * (r >> 2) + 4 * hi;
        float fr = __shfl(fac, src);
        acc0[r] *= fr;
        acc1[r] *= fr;
      }
      l_run *= fac;
      m_run = mnew;
    }
    float sum = 0.f;
#pragma unroll
    for (int i = 0; i < 16; ++i) {
      s0v[i] = __builtin_amdgcn_exp2f(s0v[i] - m_run);
      sum += s0v[i];
    }
#pragma unroll
    for (int i = 0; i < 16; ++i) {
      s1v[i] = __builtin_amdgcn_exp2f(s1v[i] - m_run);
      sum += s1v[i];
    }
    sum += __shfl_xor(sum, 32);
    l_run += sum;
    // ---- pack P into PV A-frags: cvt_pk + permlane32_swap (4 x 16-k slices) ----
    bf16x8 pa[4];
#pragma unroll
    for (int g = 0; g < 2; ++g) {
      const f32x16& s = g ? s1v : s0v;
#pragma unroll
      for (int half = 0; half < 2; ++half) {
        int o = half * 8;
        uint32_t a0 = cvtpk(s[o + 0], s[o + 1]);
        uint32_t a1 = cvtpk(s[o + 2], s[o + 3]);
        uint32_t b0 = cvtpk(s[o + 4], s[o + 5]);
        uint32_t b1 = cvtpk(s[o + 6], s[o + 7]);
        asm("v_permlane32_swap_b32 %0, %1" : "+v"(a0), "+v"(b0));
        asm("v_permlane32_swap_b32 %0, %1" : "+v"(a1), "+v"(b1));
        u32x4 w;
        w[0] = a0; w[1] = a1; w[2] = b0; w[3] = b1;
        pa[g * 2 + half] = __builtin_bit_cast(bf16x8, w);
      }
    }
    // ---- PV: O[q, d], d-halves from Vs rows l31 and 32+l31 ----
    const u16* vb = Vs[cur];
    __builtin_amdgcn_s_setprio(1);
#pragma unroll
    for (int ks = 0; ks < 4; ++ks) {
      int blk = 2 * ks + hi;
      bf16x8 vf0 = *(const bf16x8*)(vb + l31 * 64 + ((blk ^ sw) * 8));
      bf16x8 vf1 = *(const bf16x8*)(vb + (32 + l31) * 64 + ((blk ^ sw) * 8));
      acc0 = __builtin_amdgcn_mfma_f32_32x32x16_bf16(pa[ks], vf0, acc0, 0, 0, 0);
      acc1 = __builtin_amdgcn_mfma_f32_32x32x16_bf16(pa[ks], vf1, acc1, 0, 0, 0);
    }
    __builtin_amdgcn_s_setprio(0);
    __syncthreads();  // drains staged loads + guards buffer swap
  }
  // ---- epilogue ----
  float linv = 1.0f / l_run;
  u16* cb = ctx + (size_t)(b * Sq + q0) * 1024 + h * 64;
#pragma unroll
  for (int r = 0; r < 16; ++r) {
    int src = (r & 3) + 8 * (r >> 2) + 4 * hi;
    float li = __shfl(linv, src);
    cb[(size_t)src * 1024 + l31] = f2bf(acc0[r] * li);
    cb[(size_t)src * 1024 + 32 + l31] = f2bf(acc1[r] * li);
  }
}

extern "C" void kernel_launch(void* const* d_in, const int* in_sizes, int n_in,
                              void* d_out, int out_size, void* d_ws, size_t ws_size,
                              hipStream_t stream) {
  const float* v = (const float*)d_in[0];
  const float* l = (const float*)d_in[1];
  const float* ln_v_g = (const float*)d_in[2];
  const float* ln_v_b = (const float*)d_in[3];
  const float* ln_l_g = (const float*)d_in[4];
  const float* ln_l_b = (const float*)d_in[5];
  const float* gamma_v = (const float*)d_in[6];
  const float* gamma_l = (const float*)d_in[7];
  const float* Wf[8];
  const float* Bf[8];
  for (int i = 0; i < 8; ++i) {
    Wf[i] = (const float*)d_in[8 + 2 * i];
    Bf[i] = (const float*)d_in[9 + 2 * i];
  }
  float* v_out = (float*)d_out;
  float* l_out = v_out + (size_t)16384 * 1024;

  char* p = (char*)d_ws;
  auto alloc = [&](size_t bytes) {
    char* r = p;
    p += (bytes + 255) & ~(size_t)255;
    return r;
  };
  u16* Wbf[8];
  for (int i = 0; i < 8; ++i) Wbf[i] = (u16*)alloc((size_t)1024 * 1024 * 2);
  u16* vn   = (u16*)alloc((size_t)16384 * 1024 * 2);
  u16* lnm  = (u16*)alloc((size_t)4096 * 1024 * 2);
  u16* bufA = (u16*)alloc((size_t)16384 * 1024 * 2);
  u16* bufB = (u16*)alloc((size_t)4096 * 1024 * 2);
  u16* bufC = (u16*)alloc((size_t)4096 * 1024 * 2);
  u16* bufD = (u16*)alloc((size_t)16384 * 1024 * 2);

  const float QSC = 0.125f * 1.4426950408889634f;  // fold 1/sqrt(64) and log2(e) into Q

  cvt8_kernel<<<dim3(1024, 8), 256, 0, stream>>>(
      (const float4*)Wf[0], (const float4*)Wf[1], (const float4*)Wf[2], (const float4*)Wf[3],
      (const float4*)Wf[4], (const float4*)Wf[5], (const float4*)Wf[6], (const float4*)Wf[7],
      (ushort4*)Wbf[0], (ushort4*)Wbf[1], (ushort4*)Wbf[2], (ushort4*)Wbf[3],
      (ushort4*)Wbf[4], (ushort4*)Wbf[5], (ushort4*)Wbf[6], (ushort4*)Wbf[7]);
  ln_kernel<<<16384, 256, 0, stream>>>(v, ln_v_g, ln_v_b, vn);
  ln_kernel<<<4096, 256, 0, stream>>>(l, ln_l_g, ln_l_b, lnm);

  dim3 blk(256);
  dim3 blk512(512);
  // ---- v2l: q = v_norm, k/v = l_norm ----
  gemm256_kernel<0><<<dim3(256), blk512, 0, stream>>>(vn, Wbf[0], Bf[0], bufA, nullptr, nullptr, nullptr, 64, 0, QSC);
  gemm_kernel<0><<<dim3(32, 8), blk, 0, stream>>>(lnm, Wbf[1], Bf[1], bufB, nullptr, nullptr, nullptr, 0, 1.0f);
  gemm_kernel<2><<<dim3(32, 8), blk, 0, stream>>>(lnm, Wbf[2], Bf[2], bufC, nullptr, nullptr, nullptr, 9, 1.0f);
  attn_kernel<<<dim3(2048), blk, 0, stream>>>(bufA, bufB, bufC, bufD, 2048, 512, 4);
  gemm256_kernel<1><<<dim3(256), blk512, 0, stream>>>(bufD, Wbf[3], Bf[3], nullptr, v_out, v, gamma_v, 64, 0, 1.0f);
  // ---- l2v: q = l_norm, k/v = v_norm ----
  gemm_kernel<0><<<dim3(32, 8), blk, 0, stream>>>(lnm, Wbf[4], Bf[4], bufB, nullptr, nullptr, nullptr, 0, QSC);
  gemm256_kernel<0><<<dim3(256), blk512, 0, stream>>>(vn, Wbf[5], Bf[5], bufA, nullptr, nullptr, nullptr, 64, 0, 1.0f);
  gemm256_kernel<2><<<dim3(256), blk512, 0, stream>>>(vn, Wbf[6], Bf[6], bufD, nullptr, nullptr, nullptr, 64, 11, 1.0f);
  attn_kernel<<<dim3(512), blk, 0, stream>>>(bufB, bufA, bufD, bufC, 512, 2048, 2);
  gemm_kernel<1><<<dim3(32, 8), blk, 0, stream>>>(bufC, Wbf[7], Bf[7], nullptr, l_out, l, gamma_l, 0, 1.0f);
}